// Round 17
// baseline (268.827 us; speedup 1.0000x reference)
//
#include <hip/hip_runtime.h>
#include <hip/hip_bf16.h>

// SAKE GNN: B=512 graphs, M=32 atoms, H=128, L=2 layers, F_IN=16.
// R17 = R16 + ILP doubling everywhere (R16 showed latency-bound: work -42%
// VALU-busy but time -6%; chains of 4-8 dependent MFMAs + dependent
// silu/shfl with only 2 waves/SIMD to cover ~300-cyc chains):
//  - pair phase processes nt pairs (2 indep 4-MFMA chains + 2 indep
//    silu/shfl epilogues per iteration); prefetch rotation kept in pairs.
//  - U_GEMM 8-chain -> two 4-chains; t4/O/G/H 4-chains -> two 2-chains.
// Dense fallback (cnt>16, ~0.6% rows) self-loads and restores pair-0.

#define NB 512

typedef __bf16 bf16x8 __attribute__((ext_vector_type(8)));
typedef __bf16 bf16x2 __attribute__((ext_vector_type(2)));
typedef float f32x4 __attribute__((ext_vector_type(4)));

__device__ __forceinline__ unsigned short f2bf(float f) {
    unsigned int u = __float_as_uint(f);
    u = u + 0x7FFFu + ((u >> 16) & 1u);   // RNE
    return (unsigned short)(u >> 16);
}
__device__ __forceinline__ unsigned int packbf(float lo, float hi) {
    bf16x2 t;
    t.x = (__bf16)lo;
    t.y = (__bf16)hi;
    return __builtin_bit_cast(unsigned int, t);
}
__device__ __forceinline__ float bflo(unsigned int u) { return __uint_as_float(u << 16); }
__device__ __forceinline__ float bfhi(unsigned int u) { return __uint_as_float(u & 0xffff0000u); }
__device__ __forceinline__ float silu_f(float v) {
    return v * __builtin_amdgcn_rcpf(1.0f + __expf(-v));
}

// ---------------- weight transpose+bf16 prep into workspace ----------------
__global__ __launch_bounds__(256) void prep_weights(
        const float* __restrict__ We1, const float* __restrict__ We2,
        const float* __restrict__ Wh1, const float* __restrict__ Wh2,
        const float* __restrict__ W_out, const float* __restrict__ Wn1,
        unsigned short* __restrict__ ws) {
    __shared__ unsigned short t[32][33];
    const int mtx  = blockIdx.x >> 4;
    const int tile = blockIdx.x & 15;
    const int kt = tile >> 2, nt = tile & 3;
    const int tx = threadIdx.x & 31, ty = threadIdx.x >> 5;

    const int l    = (mtx < 12) ? (mtx / 6) : 0;
    const int kind = (mtx < 12) ? (mtx % 6) : (6 + (mtx - 12));
    const float* src = nullptr;
    switch (kind) {
        case 0: src = We1 + (size_t)(l*257      )*128; break;
        case 1: src = We1 + (size_t)(l*257 + 128)*128; break;
        case 2: src = We2 + (size_t)(l*128      )*128; break;
        case 3: src = Wh1 + (size_t)(l*256      )*128; break;
        case 4: src = Wh1 + (size_t)(l*256 + 128)*128; break;
        case 5: src = Wh2 + (size_t)(l*128      )*128; break;
        case 6: src = W_out; break;
        case 7: src = Wn1;  break;
    }
    #pragma unroll
    for (int r = 0; r < 4; r++) {
        int k = kt*32 + ty + r*8;
        int n = nt*32 + tx;
        t[tx][ty + r*8] = f2bf(src[(size_t)k*128 + n]);
    }
    __syncthreads();
    unsigned short* dst = ws + ((size_t)mtx << 14);
    #pragma unroll
    for (int r = 0; r < 4; r++) {
        int nl = ty + r*8;
        int n = nt*32 + nl, k = kt*32 + tx;
        dst[(size_t)n*128 + k] = t[nl][tx];
    }
}

#define MFMA16(ACC, A, B) (ACC) = __builtin_amdgcn_mfma_f32_16x16x32_bf16((A), (B), (ACC), 0, 0, 0)

// ---------------- main fused kernel: 256 threads = 4 waves ----------------
__global__ __launch_bounds__(256, 2) void sake_kernel(
    const float* __restrict__ h,   const float* __restrict__ x,
    const float* __restrict__ W_in,const float* __restrict__ b_in,
    const float* __restrict__ We1, const float* __restrict__ be1,
    const float* __restrict__ be2, const float* __restrict__ bh1,
    const float* __restrict__ bh2, const float* __restrict__ b_out,
    const float* __restrict__ bn1, const float* __restrict__ Wn2,
    const float* __restrict__ bn2, const unsigned short* __restrict__ wt,
    float* __restrict__ out)
{
    __shared__ __align__(16) float          s_d2[32*32];
    __shared__ __align__(16) float          s_hg[32*129];
    __shared__ __align__(16) unsigned short s_mimj[32*264];
    __shared__ __align__(16) unsigned short s_A1[32*136];
    __shared__ __align__(16) unsigned short s_A2[32*136];
    __shared__ __align__(16) float          s_wd[128];
    __shared__ __align__(16) float          s_be2[128];
    __shared__ __align__(16) float          s_x[32*4];
    __shared__ __align__(16) float          s_ep[256];
    __shared__ unsigned char s_nbr[32][16];
    __shared__ int           s_cnt[32];

    const int tid  = threadIdx.x;
    const int b    = blockIdx.x;
    const int w    = tid >> 6;
    const int lane = tid & 63;
    const int quad = lane >> 4;
    const int lm   = lane & 15;
    const int mt   = w & 1;
    const int ng   = w >> 1;

    // ---- load x, d2, hg = h@W_in + b_in ----
    if (tid < 32) {
        s_x[tid*4+0] = x[(b*32+tid)*3+0];
        s_x[tid*4+1] = x[(b*32+tid)*3+1];
        s_x[tid*4+2] = x[(b*32+tid)*3+2];
    }
    __syncthreads();
    for (int p = tid; p < 1024; p += 256) {
        int i = p >> 5, j = p & 31;
        float dx = s_x[i*4+0]-s_x[j*4+0];
        float dy = s_x[i*4+1]-s_x[j*4+1];
        float dz = s_x[i*4+2]-s_x[j*4+2];
        s_d2[p] = dx*dx + dy*dy + dz*dz;
    }
    {
        int k = tid & 127, mg = tid >> 7;
        float c0 = W_in[       k], c1 = W_in[ 128+k], c2 = W_in[ 256+k], c3 = W_in[ 384+k];
        float c4 = W_in[ 512+k], c5 = W_in[ 640+k], c6 = W_in[ 768+k], c7 = W_in[ 896+k];
        float c8 = W_in[1024+k], c9 = W_in[1152+k], c10= W_in[1280+k], c11= W_in[1408+k];
        float c12= W_in[1536+k], c13= W_in[1664+k], c14= W_in[1792+k], c15= W_in[1920+k];
        float bi = b_in[k];
        for (int rr = 0; rr < 16; rr++) {
            int m = mg*16 + rr;
            const float4* h4 = (const float4*)(h + (size_t)(b*32 + m)*16);
            float4 h0 = h4[0], h1 = h4[1], h2 = h4[2], h3 = h4[3];
            float acc = bi
                + h0.x*c0  + h0.y*c1  + h0.z*c2  + h0.w*c3
                + h1.x*c4  + h1.y*c5  + h1.z*c6  + h1.w*c7
                + h2.x*c8  + h2.y*c9  + h2.z*c10 + h2.w*c11
                + h3.x*c12 + h3.y*c13 + h3.z*c14 + h3.w*c15;
            s_hg[m*129 + k] = acc;
        }
    }
    __syncthreads();

    // ---- build compacted neighbor lists (layer-invariant) ----
    if (tid < 32) {
        int c = 0;
        for (int j = 0; j < 32; j++) {
            if (s_d2[tid*32 + j] < 1.0f && j != tid) {
                if (c < 16) s_nbr[tid][c] = (unsigned char)j;
                c++;
            }
        }
        for (int q = c; q < 16; q++) s_nbr[tid][q] = (unsigned char)tid;
        s_cnt[tid] = c;
    }

    for (int l = 0; l < 2; l++) {
        // ---- stage hg -> bf16 A1, load wd/be2 ----
        {
            int m = tid >> 3, c = (tid & 7) * 16;
            const float* hp = &s_hg[m*129 + c];
            uint4 pa, pb;
            pa.x = packbf(hp[0],  hp[1]);  pa.y = packbf(hp[2],  hp[3]);
            pa.z = packbf(hp[4],  hp[5]);  pa.w = packbf(hp[6],  hp[7]);
            pb.x = packbf(hp[8],  hp[9]);  pb.y = packbf(hp[10], hp[11]);
            pb.z = packbf(hp[12], hp[13]); pb.w = packbf(hp[14], hp[15]);
            *(uint4*)&s_A1[m*136 + c]     = pa;
            *(uint4*)&s_A1[m*136 + c + 8] = pb;
        }
        if (tid < 128) {
            s_wd[tid]  = We1[(l*257 + 256)*128 + tid];
            s_be2[tid] = be2[l*128 + tid];
        }
        __syncthreads();

        // ---- mi | mj GEMM (split 2x2 chains) ----
        #pragma unroll 1
        for (int t4 = 0; t4 < 8; t4++) {
            int nt = ng + t4*2;
            const unsigned short* bt = wt + (((size_t)l*6 + (nt < 8 ? 0 : 1)) << 14);
            int ncl = (nt & 7)*16 + lm;
            f32x4 acca = {0.f,0.f,0.f,0.f}, accb = {0.f,0.f,0.f,0.f};
            {
                bf16x8 a0 = *(const bf16x8*)&s_A1[(mt*16+lm)*136 +  0 + quad*8];
                bf16x8 a1 = *(const bf16x8*)&s_A1[(mt*16+lm)*136 + 32 + quad*8];
                bf16x8 a2 = *(const bf16x8*)&s_A1[(mt*16+lm)*136 + 64 + quad*8];
                bf16x8 a3 = *(const bf16x8*)&s_A1[(mt*16+lm)*136 + 96 + quad*8];
                bf16x8 w0 = *(const bf16x8*)&bt[ncl*128 +  0 + quad*8];
                bf16x8 w1 = *(const bf16x8*)&bt[ncl*128 + 32 + quad*8];
                bf16x8 w2 = *(const bf16x8*)&bt[ncl*128 + 64 + quad*8];
                bf16x8 w3 = *(const bf16x8*)&bt[ncl*128 + 96 + quad*8];
                MFMA16(acca, a0, w0); MFMA16(accb, a1, w1);
                MFMA16(acca, a2, w2); MFMA16(accb, a3, w3);
            }
            f32x4 acc = acca + accb;
            int c = nt*16 + lm;
            float bias = (nt >= 8) ? be1[l*128 + ncl] : 0.0f;
            s_mimj[(mt*16 + quad*4 + 0)*264 + c] = f2bf(acc.x + bias);
            s_mimj[(mt*16 + quad*4 + 1)*264 + c] = f2bf(acc.y + bias);
            s_mimj[(mt*16 + quad*4 + 2)*264 + c] = f2bf(acc.z + bias);
            s_mimj[(mt*16 + quad*4 + 3)*264 + c] = f2bf(acc.w + bias);
        }
        __syncthreads();

        // ---- pair phase: sparse (paired-nt) / dense fallback ----
        {
            const unsigned short* we2t = wt + (((size_t)l*6 + 2) << 14);
            const unsigned short* bbase = we2t + lm*128 + quad*8;   // + nt*2048
            // prologue: pair 0 (nt=0,1) B-frags
            bf16x8 c00 = *(const bf16x8*)(bbase        );
            bf16x8 c01 = *(const bf16x8*)(bbase +   32 );
            bf16x8 c02 = *(const bf16x8*)(bbase +   64 );
            bf16x8 c03 = *(const bf16x8*)(bbase +   96 );
            bf16x8 c10 = *(const bf16x8*)(bbase + 2048 );
            bf16x8 c11 = *(const bf16x8*)(bbase + 2080 );
            bf16x8 c12 = *(const bf16x8*)(bbase + 2112 );
            bf16x8 c13 = *(const bf16x8*)(bbase + 2144 );
            #pragma unroll 1
            for (int ii = 0; ii < 8; ii++) {
                const int i = ii*4 + w;
                const int cnt = s_cnt[i];
                const uint4 miu0 = *(const uint4*)&s_mimj[i*264 +  0 + quad*8];
                const uint4 miu1 = *(const uint4*)&s_mimj[i*264 + 32 + quad*8];
                const uint4 miu2 = *(const uint4*)&s_mimj[i*264 + 64 + quad*8];
                const uint4 miu3 = *(const uint4*)&s_mimj[i*264 + 96 + quad*8];
#define MAKE_AF(J, KB, MIU, AF) { \
    const uint4 mju = *(const uint4*)&s_mimj[(J)*264 + 128 + (KB)*32 + quad*8]; \
    const float4 wa = *(const float4*)&s_wd[(KB)*32 + quad*8]; \
    const float4 wb = *(const float4*)&s_wd[(KB)*32 + quad*8 + 4]; \
    uint4 au; \
    au.x = packbf(silu_f(bflo(MIU.x)+bflo(mju.x)+d2v*wa.x), silu_f(bfhi(MIU.x)+bfhi(mju.x)+d2v*wa.y)); \
    au.y = packbf(silu_f(bflo(MIU.y)+bflo(mju.y)+d2v*wa.z), silu_f(bfhi(MIU.y)+bfhi(mju.y)+d2v*wa.w)); \
    au.z = packbf(silu_f(bflo(MIU.z)+bflo(mju.z)+d2v*wb.x), silu_f(bfhi(MIU.z)+bfhi(mju.z)+d2v*wb.y)); \
    au.w = packbf(silu_f(bflo(MIU.w)+bflo(mju.w)+d2v*wb.z), silu_f(bfhi(MIU.w)+bfhi(mju.w)+d2v*wb.w)); \
    AF = __builtin_bit_cast(bf16x8, au); }
                if (cnt <= 16) {
                    // ---- compacted single-tile, paired-nt path ----
                    const int j = s_nbr[i][lm];
                    const float d2v = s_d2[i*32 + j];
                    bf16x8 a00, a01, a02, a03;
                    MAKE_AF(j, 0, miu0, a00) MAKE_AF(j, 1, miu1, a01)
                    MAKE_AF(j, 2, miu2, a02) MAKE_AF(j, 3, miu3, a03)
                    const int jb0 = quad*4;
                    const float mk00 = (jb0 + 0 < cnt) ? 1.f : 0.f;
                    const float mk01 = (jb0 + 1 < cnt) ? 1.f : 0.f;
                    const float mk02 = (jb0 + 2 < cnt) ? 1.f : 0.f;
                    const float mk03 = (jb0 + 3 < cnt) ? 1.f : 0.f;
                    #pragma unroll 1
                    for (int p = 0; p < 4; p++) {
                        const unsigned short* np = bbase + (((p + 1) & 3) * 4096);
                        bf16x8 n00 = *(const bf16x8*)(np        );
                        bf16x8 n01 = *(const bf16x8*)(np +   32 );
                        bf16x8 n02 = *(const bf16x8*)(np +   64 );
                        bf16x8 n03 = *(const bf16x8*)(np +   96 );
                        bf16x8 n10 = *(const bf16x8*)(np + 2048 );
                        bf16x8 n11 = *(const bf16x8*)(np + 2080 );
                        bf16x8 n12 = *(const bf16x8*)(np + 2112 );
                        bf16x8 n13 = *(const bf16x8*)(np + 2144 );
                        f32x4 ac0 = {0.f,0.f,0.f,0.f};
                        f32x4 ac1 = {0.f,0.f,0.f,0.f};
                        MFMA16(ac0, a00, c00); MFMA16(ac1, a00, c10);
                        MFMA16(ac0, a01, c01); MFMA16(ac1, a01, c11);
                        MFMA16(ac0, a02, c02); MFMA16(ac1, a02, c12);
                        MFMA16(ac0, a03, c03); MFMA16(ac1, a03, c13);
                        const float bv0 = s_be2[p*32      + lm];
                        const float bv1 = s_be2[p*32 + 16 + lm];
                        float part0 = mk00*silu_f(ac0.x + bv0) + mk01*silu_f(ac0.y + bv0)
                                    + mk02*silu_f(ac0.z + bv0) + mk03*silu_f(ac0.w + bv0);
                        float part1 = mk00*silu_f(ac1.x + bv1) + mk01*silu_f(ac1.y + bv1)
                                    + mk02*silu_f(ac1.z + bv1) + mk03*silu_f(ac1.w + bv1);
                        part0 += __shfl_xor(part0, 16);
                        part1 += __shfl_xor(part1, 16);
                        part0 += __shfl_xor(part0, 32);
                        part1 += __shfl_xor(part1, 32);
                        if (lane < 16) {
                            s_A2[i*136 + (p*2    )*16 + lane] = f2bf(part0);
                            s_A2[i*136 + (p*2 + 1)*16 + lane] = f2bf(part1);
                        }
                        c00 = n00; c01 = n01; c02 = n02; c03 = n03;
                        c10 = n10; c11 = n11; c12 = n12; c13 = n13;
                    }
                } else {
                    // ---- dense 2-tile fallback (rare); self-loads, restores pair 0 ----
                    bf16x8 a00, a01, a02, a03;
                    bf16x8 a10, a11, a12, a13;
                    {
                        const int j = lm;
                        const float d2v = s_d2[i*32 + j];
                        MAKE_AF(j, 0, miu0, a00) MAKE_AF(j, 1, miu1, a01)
                        MAKE_AF(j, 2, miu2, a02) MAKE_AF(j, 3, miu3, a03)
                    }
                    {
                        const int j = 16 + lm;
                        const float d2v = s_d2[i*32 + j];
                        MAKE_AF(j, 0, miu0, a10) MAKE_AF(j, 1, miu1, a11)
                        MAKE_AF(j, 2, miu2, a12) MAKE_AF(j, 3, miu3, a13)
                    }
                    const int jb0 = quad*4, jb1 = 16 + quad*4;
                    const float mk00 = (s_d2[i*32 + jb0 + 0] < 1.0f && (jb0+0) != i) ? 1.f : 0.f;
                    const float mk01 = (s_d2[i*32 + jb0 + 1] < 1.0f && (jb0+1) != i) ? 1.f : 0.f;
                    const float mk02 = (s_d2[i*32 + jb0 + 2] < 1.0f && (jb0+2) != i) ? 1.f : 0.f;
                    const float mk03 = (s_d2[i*32 + jb0 + 3] < 1.0f && (jb0+3) != i) ? 1.f : 0.f;
                    const float mk10 = (s_d2[i*32 + jb1 + 0] < 1.0f && (jb1+0) != i) ? 1.f : 0.f;
                    const float mk11 = (s_d2[i*32 + jb1 + 1] < 1.0f && (jb1+1) != i) ? 1.f : 0.f;
                    const float mk12 = (s_d2[i*32 + jb1 + 2] < 1.0f && (jb1+2) != i) ? 1.f : 0.f;
                    const float mk13 = (s_d2[i*32 + jb1 + 3] < 1.0f && (jb1+3) != i) ? 1.f : 0.f;
                    #pragma unroll 1
                    for (int nt = 0; nt < 8; nt++) {
                        const unsigned short* bp = bbase + nt*2048;
                        bf16x8 d0 = *(const bf16x8*)(bp      );
                        bf16x8 d1 = *(const bf16x8*)(bp +  32);
                        bf16x8 d2b= *(const bf16x8*)(bp +  64);
                        bf16x8 d3 = *(const bf16x8*)(bp +  96);
                        f32x4 ac0 = {0.f,0.f,0.f,0.f};
                        f32x4 ac1 = {0.f,0.f,0.f,0.f};
                        MFMA16(ac0, a00, d0); MFMA16(ac1, a10, d0);
                        MFMA16(ac0, a01, d1); MFMA16(ac1, a11, d1);
                        MFMA16(ac0, a02, d2b);MFMA16(ac1, a12, d2b);
                        MFMA16(ac0, a03, d3); MFMA16(ac1, a13, d3);
                        const float bv = s_be2[nt*16 + lm];
                        float part = mk00*silu_f(ac0.x + bv) + mk01*silu_f(ac0.y + bv)
                                   + mk02*silu_f(ac0.z + bv) + mk03*silu_f(ac0.w + bv)
                                   + mk10*silu_f(ac1.x + bv) + mk11*silu_f(ac1.y + bv)
                                   + mk12*silu_f(ac1.z + bv) + mk13*silu_f(ac1.w + bv);
                        part += __shfl_xor(part, 16);
                        part += __shfl_xor(part, 32);
                        if (lane < 16) s_A2[i*136 + nt*16 + lane] = f2bf(part);
                    }
                    // restore pair-0 rotation state for subsequent ii iterations
                    c00 = *(const bf16x8*)(bbase        );
                    c01 = *(const bf16x8*)(bbase +   32 );
                    c02 = *(const bf16x8*)(bbase +   64 );
                    c03 = *(const bf16x8*)(bbase +   96 );
                    c10 = *(const bf16x8*)(bbase + 2048 );
                    c11 = *(const bf16x8*)(bbase + 2080 );
                    c12 = *(const bf16x8*)(bbase + 2112 );
                    c13 = *(const bf16x8*)(bbase + 2144 );
                }
#undef MAKE_AF
            }
        }
        __syncthreads();

        // ---- u = silu(hg@Wh1a + agg@Wh1b + bh1) (two independent 4-chains) ----
        unsigned short* s_u = s_mimj;
        {
            const unsigned short* w1a = wt + (((size_t)l*6 + 3) << 14);
            const unsigned short* w1b = wt + (((size_t)l*6 + 4) << 14);
#define U_GEMM(T2) { \
    const int nt = ng + (T2)*2, ncl = nt*16 + lm; \
    f32x4 acca = {0.f,0.f,0.f,0.f}, accb = {0.f,0.f,0.f,0.f}; \
    _Pragma("unroll") \
    for (int kb = 0; kb < 4; kb++) { \
        bf16x8 aa  = *(const bf16x8*)&s_A1[(mt*16+lm)*136 + kb*32 + quad*8]; \
        bf16x8 ba  = *(const bf16x8*)&w1a[ncl*128 + kb*32 + quad*8]; \
        bf16x8 ab  = *(const bf16x8*)&s_A2[(mt*16+lm)*136 + kb*32 + quad*8]; \
        bf16x8 bb2 = *(const bf16x8*)&w1b[ncl*128 + kb*32 + quad*8]; \
        MFMA16(acca, aa, ba); MFMA16(accb, ab, bb2); } \
    f32x4 acc = acca + accb; \
    const float bh = bh1[l*128 + ncl]; \
    s_u[(mt*16 + quad*4 + 0)*136 + ncl] = f2bf(silu_f(acc.x + bh)); \
    s_u[(mt*16 + quad*4 + 1)*136 + ncl] = f2bf(silu_f(acc.y + bh)); \
    s_u[(mt*16 + quad*4 + 2)*136 + ncl] = f2bf(silu_f(acc.z + bh)); \
    s_u[(mt*16 + quad*4 + 3)*136 + ncl] = f2bf(silu_f(acc.w + bh)); }
            U_GEMM(0) U_GEMM(1) U_GEMM(2) U_GEMM(3)
#undef U_GEMM
        }
        __syncthreads();

        // ---- hg += u@Wh2 + bh2 (split 2x2 chains) ----
        {
            const unsigned short* w2 = wt + (((size_t)l*6 + 5) << 14);
#define H_GEMM(T2) { \
    const int nt = ng + (T2)*2, ncl = nt*16 + lm; \
    f32x4 acca = {0.f,0.f,0.f,0.f}, accb = {0.f,0.f,0.f,0.f}; \
    { \
        bf16x8 a0 = *(const bf16x8*)&s_u[(mt*16+lm)*136 +  0 + quad*8]; \
        bf16x8 a1 = *(const bf16x8*)&s_u[(mt*16+lm)*136 + 32 + quad*8]; \
        bf16x8 a2 = *(const bf16x8*)&s_u[(mt*16+lm)*136 + 64 + quad*8]; \
        bf16x8 a3 = *(const bf16x8*)&s_u[(mt*16+lm)*136 + 96 + quad*8]; \
        bf16x8 w0 = *(const bf16x8*)&w2[ncl*128 +  0 + quad*8]; \
        bf16x8 w1 = *(const bf16x8*)&w2[ncl*128 + 32 + quad*8]; \
        bf16x8 w2v= *(const bf16x8*)&w2[ncl*128 + 64 + quad*8]; \
        bf16x8 w3 = *(const bf16x8*)&w2[ncl*128 + 96 + quad*8]; \
        MFMA16(acca, a0, w0); MFMA16(accb, a1, w1); \
        MFMA16(acca, a2, w2v); MFMA16(accb, a3, w3); \
    } \
    f32x4 acc = acca + accb; \
    const float bh = bh2[l*128 + ncl]; \
    s_hg[(mt*16 + quad*4 + 0)*129 + ncl] += acc.x + bh; \
    s_hg[(mt*16 + quad*4 + 1)*129 + ncl] += acc.y + bh; \
    s_hg[(mt*16 + quad*4 + 2)*129 + ncl] += acc.z + bh; \
    s_hg[(mt*16 + quad*4 + 3)*129 + ncl] += acc.w + bh; }
            H_GEMM(0) H_GEMM(1) H_GEMM(2) H_GEMM(3)
#undef H_GEMM
        }
        __syncthreads();
    }

    // ---- output head ----
    {
        int m = tid >> 3, c = (tid & 7) * 16;
        const float* hp = &s_hg[m*129 + c];
        uint4 pa, pb;
        pa.x = packbf(hp[0],  hp[1]);  pa.y = packbf(hp[2],  hp[3]);
        pa.z = packbf(hp[4],  hp[5]);  pa.w = packbf(hp[6],  hp[7]);
        pb.x = packbf(hp[8],  hp[9]);  pb.y = packbf(hp[10], hp[11]);
        pb.z = packbf(hp[12], hp[13]); pb.w = packbf(hp[14], hp[15]);
        *(uint4*)&s_A1[m*136 + c]     = pa;
        *(uint4*)&s_A1[m*136 + c + 8] = pb;
    }
    __syncthreads();
    {   // ho = hg@W_out + b_out -> A2 (bf16) (split 2x2)
        const unsigned short* wo = wt + ((size_t)12 << 14);
#define O_GEMM(T2) { \
    const int nt = ng + (T2)*2, ncl = nt*16 + lm; \
    f32x4 acca = {0.f,0.f,0.f,0.f}, accb = {0.f,0.f,0.f,0.f}; \
    { \
        bf16x8 a0 = *(const bf16x8*)&s_A1[(mt*16+lm)*136 +  0 + quad*8]; \
        bf16x8 a1 = *(const bf16x8*)&s_A1[(mt*16+lm)*136 + 32 + quad*8]; \
        bf16x8 a2 = *(const bf16x8*)&s_A1[(mt*16+lm)*136 + 64 + quad*8]; \
        bf16x8 a3 = *(const bf16x8*)&s_A1[(mt*16+lm)*136 + 96 + quad*8]; \
        bf16x8 w0 = *(const bf16x8*)&wo[ncl*128 +  0 + quad*8]; \
        bf16x8 w1 = *(const bf16x8*)&wo[ncl*128 + 32 + quad*8]; \
        bf16x8 w2v= *(const bf16x8*)&wo[ncl*128 + 64 + quad*8]; \
        bf16x8 w3 = *(const bf16x8*)&wo[ncl*128 + 96 + quad*8]; \
        MFMA16(acca, a0, w0); MFMA16(accb, a1, w1); \
        MFMA16(acca, a2, w2v); MFMA16(accb, a3, w3); \
    } \
    f32x4 acc = acca + accb; \
    const float bo = b_out[ncl]; \
    s_A2[(mt*16 + quad*4 + 0)*136 + ncl] = f2bf(acc.x + bo); \
    s_A2[(mt*16 + quad*4 + 1)*136 + ncl] = f2bf(acc.y + bo); \
    s_A2[(mt*16 + quad*4 + 2)*136 + ncl] = f2bf(acc.z + bo); \
    s_A2[(mt*16 + quad*4 + 3)*136 + ncl] = f2bf(acc.w + bo); }
        O_GEMM(0) O_GEMM(1) O_GEMM(2) O_GEMM(3)
#undef O_GEMM
    }
    __syncthreads();
    float* s_g = (float*)s_mimj;
    {   // g = silu(ho@Wn1 + bn1) -> s_g fp32 (split 2x2)
        const unsigned short* wn1 = wt + ((size_t)13 << 14);
#define G_GEMM(T2) { \
    const int nt = ng + (T2)*2, ncl = nt*16 + lm; \
    f32x4 acca = {0.f,0.f,0.f,0.f}, accb = {0.f,0.f,0.f,0.f}; \
    { \
        bf16x8 a0 = *(const bf16x8*)&s_A2[(mt*16+lm)*136 +  0 + quad*8]; \
        bf16x8 a1 = *(const bf16x8*)&s_A2[(mt*16+lm)*136 + 32 + quad*8]; \
        bf16x8 a2 = *(const bf16x8*)&s_A2[(mt*16+lm)*136 + 64 + quad*8]; \
        bf16x8 a3 = *(const bf16x8*)&s_A2[(mt*16+lm)*136 + 96 + quad*8]; \
        bf16x8 w0 = *(const bf16x8*)&wn1[ncl*128 +  0 + quad*8]; \
        bf16x8 w1 = *(const bf16x8*)&wn1[ncl*128 + 32 + quad*8]; \
        bf16x8 w2v= *(const bf16x8*)&wn1[ncl*128 + 64 + quad*8]; \
        bf16x8 w3 = *(const bf16x8*)&wn1[ncl*128 + 96 + quad*8]; \
        MFMA16(acca, a0, w0); MFMA16(accb, a1, w1); \
        MFMA16(acca, a2, w2v); MFMA16(accb, a3, w3); \
    } \
    f32x4 acc = acca + accb; \
    const float bn = bn1[ncl]; \
    s_g[(mt*16 + quad*4 + 0)*129 + ncl] = silu_f(acc.x + bn); \
    s_g[(mt*16 + quad*4 + 1)*129 + ncl] = silu_f(acc.y + bn); \
    s_g[(mt*16 + quad*4 + 2)*129 + ncl] = silu_f(acc.z + bn); \
    s_g[(mt*16 + quad*4 + 3)*129 + ncl] = silu_f(acc.w + bn); }
        G_GEMM(0) G_GEMM(1) G_GEMM(2) G_GEMM(3)
#undef G_GEMM
    }
    __syncthreads();
    // e = g @ Wn2 + bn2 ; out[b] = sum_m e[m]
    {
        int m = tid >> 3, s = tid & 7;
        float acc = 0.f;
        #pragma unroll
        for (int q = 0; q < 16; q++) {
            int hh = s*16 + q;
            acc += s_g[m*129 + hh] * Wn2[hh];
        }
        s_ep[tid] = acc;
    }
    __syncthreads();
    if (tid < 32) {
        float e = bn2[0];
        #pragma unroll
        for (int s = 0; s < 8; s++) e += s_ep[tid*8 + s];
        #pragma unroll
        for (int off = 16; off >= 1; off >>= 1) e += __shfl_down(e, off, 32);
        if (tid == 0) out[b] = e;
    }
}

extern "C" void kernel_launch(void* const* d_in, const int* in_sizes, int n_in,
                              void* d_out, int out_size, void* d_ws, size_t ws_size,
                              hipStream_t stream) {
    const float* h     = (const float*)d_in[0];
    const float* x     = (const float*)d_in[1];
    const float* W_in  = (const float*)d_in[3];
    const float* b_in  = (const float*)d_in[4];
    const float* We1   = (const float*)d_in[5];
    const float* be1   = (const float*)d_in[6];
    const float* We2   = (const float*)d_in[7];
    const float* be2   = (const float*)d_in[8];
    const float* Wh1   = (const float*)d_in[9];
    const float* bh1   = (const float*)d_in[10];
    const float* Wh2   = (const float*)d_in[11];
    const float* bh2   = (const float*)d_in[12];
    const float* W_out = (const float*)d_in[13];
    const float* b_out = (const float*)d_in[14];
    const float* Wn1   = (const float*)d_in[15];
    const float* bn1   = (const float*)d_in[16];
    const float* Wn2   = (const float*)d_in[17];
    const float* bn2   = (const float*)d_in[18];
    unsigned short* ws = (unsigned short*)d_ws;   // needs 14*16384*2 = 448 KB
    float* outp = (float*)d_out;

    prep_weights<<<14*16, 256, 0, stream>>>(We1, We2, Wh1, Wh2, W_out, Wn1, ws);
    sake_kernel<<<NB, 256, 0, stream>>>(h, x, W_in, b_in, We1, be1, be2, bh1, bh2,
                                        b_out, bn1, Wn2, bn2, ws, outp);
}

// Round 18
// 255.924 us; speedup vs baseline: 1.0504x; 1.0504x over previous
//
#include <hip/hip_runtime.h>
#include <hip/hip_bf16.h>

// SAKE GNN: B=512 graphs, M=32 atoms, H=128, L=2 layers, F_IN=16.
// R18 = revert to R16, the measured best (181us dispatch / 257us bench).
// R17's ILP doubling regressed (191us): stall is NOT MFMA-chain latency but
// distributed small latencies uncoverable at 2 waves/SIMD (hard cap: unified
// reg bucket (128,256] -> 2 waves; R7/R12/R14 all failed to break it).
// R16 design: sparse pair phase — compact each row's <=16 neighbors into one
// 16-wide j-tile (pad=self, mask jc<cnt); dense 2-tile fallback for rare
// cnt>16 rows. Ladder: 677(R1 spills) -> 248(R6 no-spill) -> 222(R8 rcp-silu)
// -> 204(R10 2-block) -> 185(R11 dbuf) -> 181(R16 sparse).

#define NB 512

typedef __bf16 bf16x8 __attribute__((ext_vector_type(8)));
typedef __bf16 bf16x2 __attribute__((ext_vector_type(2)));
typedef float f32x4 __attribute__((ext_vector_type(4)));

__device__ __forceinline__ unsigned short f2bf(float f) {
    unsigned int u = __float_as_uint(f);
    u = u + 0x7FFFu + ((u >> 16) & 1u);   // RNE
    return (unsigned short)(u >> 16);
}
__device__ __forceinline__ unsigned int packbf(float lo, float hi) {
    bf16x2 t;
    t.x = (__bf16)lo;                     // RNE hw cvt; pair fuses to v_cvt_pk_bf16_f32
    t.y = (__bf16)hi;
    return __builtin_bit_cast(unsigned int, t);
}
__device__ __forceinline__ float bflo(unsigned int u) { return __uint_as_float(u << 16); }
__device__ __forceinline__ float bfhi(unsigned int u) { return __uint_as_float(u & 0xffff0000u); }
__device__ __forceinline__ float silu_f(float v) {
    return v * __builtin_amdgcn_rcpf(1.0f + __expf(-v));
}

// ---------------- weight transpose+bf16 prep into workspace ----------------
// ws layout (each matrix 128x128 = 16384 bf16, stored as WT[n][k] = W[k][n]):
//   l*6 + {0:WaT, 1:WbT, 2:We2T, 3:Wh1aT, 4:Wh1bT, 5:Wh2T}, 12:W_outT, 13:Wn1T
__global__ __launch_bounds__(256) void prep_weights(
        const float* __restrict__ We1, const float* __restrict__ We2,
        const float* __restrict__ Wh1, const float* __restrict__ Wh2,
        const float* __restrict__ W_out, const float* __restrict__ Wn1,
        unsigned short* __restrict__ ws) {
    __shared__ unsigned short t[32][33];
    const int mtx  = blockIdx.x >> 4;       // 0..13
    const int tile = blockIdx.x & 15;
    const int kt = tile >> 2, nt = tile & 3;
    const int tx = threadIdx.x & 31, ty = threadIdx.x >> 5;   // ty 0..7

    const int l    = (mtx < 12) ? (mtx / 6) : 0;
    const int kind = (mtx < 12) ? (mtx % 6) : (6 + (mtx - 12));
    const float* src = nullptr;
    switch (kind) {
        case 0: src = We1 + (size_t)(l*257      )*128; break;  // Wa
        case 1: src = We1 + (size_t)(l*257 + 128)*128; break;  // Wb
        case 2: src = We2 + (size_t)(l*128      )*128; break;
        case 3: src = Wh1 + (size_t)(l*256      )*128; break;  // Wh1a
        case 4: src = Wh1 + (size_t)(l*256 + 128)*128; break;  // Wh1b
        case 5: src = Wh2 + (size_t)(l*128      )*128; break;
        case 6: src = W_out; break;
        case 7: src = Wn1;  break;
    }
    #pragma unroll
    for (int r = 0; r < 4; r++) {
        int k = kt*32 + ty + r*8;
        int n = nt*32 + tx;
        t[tx][ty + r*8] = f2bf(src[(size_t)k*128 + n]);
    }
    __syncthreads();
    unsigned short* dst = ws + ((size_t)mtx << 14);
    #pragma unroll
    for (int r = 0; r < 4; r++) {
        int nl = ty + r*8;
        int n = nt*32 + nl, k = kt*32 + tx;
        dst[(size_t)n*128 + k] = t[nl][tx];
    }
}

#define MFMA16(ACC, A, B) (ACC) = __builtin_amdgcn_mfma_f32_16x16x32_bf16((A), (B), (ACC), 0, 0, 0)

// ---------------- main fused kernel: 256 threads = 4 waves ----------------
__global__ __launch_bounds__(256, 2) void sake_kernel(
    const float* __restrict__ h,   const float* __restrict__ x,
    const float* __restrict__ W_in,const float* __restrict__ b_in,
    const float* __restrict__ We1, const float* __restrict__ be1,
    const float* __restrict__ be2, const float* __restrict__ bh1,
    const float* __restrict__ bh2, const float* __restrict__ b_out,
    const float* __restrict__ bn1, const float* __restrict__ Wn2,
    const float* __restrict__ bn2, const unsigned short* __restrict__ wt,
    float* __restrict__ out)
{
    __shared__ __align__(16) float          s_d2[32*32];      // 4 KB
    __shared__ __align__(16) float          s_hg[32*129];     // 16.1 KB fp32 residual
    __shared__ __align__(16) unsigned short s_mimj[32*264];   // 16.9 KB (mi|mj+be1); reused: u / g fp32
    __shared__ __align__(16) unsigned short s_A1[32*136];     // 8.5 KB bf16 A-stage (hgb)
    __shared__ __align__(16) unsigned short s_A2[32*136];     // 8.5 KB bf16 A-stage (agg / ho)
    __shared__ __align__(16) float          s_wd[128];
    __shared__ __align__(16) float          s_be2[128];
    __shared__ __align__(16) float          s_x[32*4];
    __shared__ __align__(16) float          s_ep[256];
    __shared__ unsigned char s_nbr[32][16];                   // compacted neighbor lists
    __shared__ int           s_cnt[32];

    const int tid  = threadIdx.x;
    const int b    = blockIdx.x;
    const int w    = tid >> 6;        // wave 0..3
    const int lane = tid & 63;
    const int quad = lane >> 4;
    const int lm   = lane & 15;
    const int mt   = w & 1;           // row-half for 32-row GEMMs
    const int ng   = w >> 1;          // col-tile group (0..1)

    // ---- load x, d2, hg = h@W_in + b_in ----
    if (tid < 32) {
        s_x[tid*4+0] = x[(b*32+tid)*3+0];
        s_x[tid*4+1] = x[(b*32+tid)*3+1];
        s_x[tid*4+2] = x[(b*32+tid)*3+2];
    }
    __syncthreads();
    for (int p = tid; p < 1024; p += 256) {
        int i = p >> 5, j = p & 31;
        float dx = s_x[i*4+0]-s_x[j*4+0];
        float dy = s_x[i*4+1]-s_x[j*4+1];
        float dz = s_x[i*4+2]-s_x[j*4+2];
        s_d2[p] = dx*dx + dy*dy + dz*dz;
    }
    {
        int k = tid & 127, mg = tid >> 7;   // mg 0..1 -> 16 rows each
        float c0 = W_in[       k], c1 = W_in[ 128+k], c2 = W_in[ 256+k], c3 = W_in[ 384+k];
        float c4 = W_in[ 512+k], c5 = W_in[ 640+k], c6 = W_in[ 768+k], c7 = W_in[ 896+k];
        float c8 = W_in[1024+k], c9 = W_in[1152+k], c10= W_in[1280+k], c11= W_in[1408+k];
        float c12= W_in[1536+k], c13= W_in[1664+k], c14= W_in[1792+k], c15= W_in[1920+k];
        float bi = b_in[k];
        for (int rr = 0; rr < 16; rr++) {
            int m = mg*16 + rr;
            const float4* h4 = (const float4*)(h + (size_t)(b*32 + m)*16);
            float4 h0 = h4[0], h1 = h4[1], h2 = h4[2], h3 = h4[3];
            float acc = bi
                + h0.x*c0  + h0.y*c1  + h0.z*c2  + h0.w*c3
                + h1.x*c4  + h1.y*c5  + h1.z*c6  + h1.w*c7
                + h2.x*c8  + h2.y*c9  + h2.z*c10 + h2.w*c11
                + h3.x*c12 + h3.y*c13 + h3.z*c14 + h3.w*c15;
            s_hg[m*129 + k] = acc;
        }
    }
    __syncthreads();

    // ---- build compacted neighbor lists (d2 is layer-invariant) ----
    if (tid < 32) {
        int c = 0;
        for (int j = 0; j < 32; j++) {
            if (s_d2[tid*32 + j] < 1.0f && j != tid) {
                if (c < 16) s_nbr[tid][c] = (unsigned char)j;
                c++;
            }
        }
        for (int q = c; q < 16; q++) s_nbr[tid][q] = (unsigned char)tid;  // pad = self
        s_cnt[tid] = c;
    }

    for (int l = 0; l < 2; l++) {
        // ---- stage hg -> bf16 A1 (packed uint4 stores), load wd/be2 ----
        {
            int m = tid >> 3, c = (tid & 7) * 16;
            const float* hp = &s_hg[m*129 + c];
            uint4 pa, pb;
            pa.x = packbf(hp[0],  hp[1]);  pa.y = packbf(hp[2],  hp[3]);
            pa.z = packbf(hp[4],  hp[5]);  pa.w = packbf(hp[6],  hp[7]);
            pb.x = packbf(hp[8],  hp[9]);  pb.y = packbf(hp[10], hp[11]);
            pb.z = packbf(hp[12], hp[13]); pb.w = packbf(hp[14], hp[15]);
            *(uint4*)&s_A1[m*136 + c]     = pa;
            *(uint4*)&s_A1[m*136 + c + 8] = pb;
        }
        if (tid < 128) {
            s_wd[tid]  = We1[(l*257 + 256)*128 + tid];
            s_be2[tid] = be2[l*128 + tid];
        }
        __syncthreads();

        // ---- mi | mj GEMM: [32x128] @ [Wa | Wb] -> s_mimj (be1 folded into mj) ----
        #pragma unroll 1
        for (int t4 = 0; t4 < 8; t4++) {
            int nt = ng + t4*2;                       // 0..15
            const unsigned short* bt = wt + (((size_t)l*6 + (nt < 8 ? 0 : 1)) << 14);
            int ncl = (nt & 7)*16 + lm;
            f32x4 acc = {0.f,0.f,0.f,0.f};
            #pragma unroll
            for (int kb = 0; kb < 4; kb++) {
                bf16x8 a  = *(const bf16x8*)&s_A1[(mt*16+lm)*136 + kb*32 + quad*8];
                bf16x8 bb = *(const bf16x8*)&bt[ncl*128 + kb*32 + quad*8];
                MFMA16(acc, a, bb);
            }
            int c = nt*16 + lm;
            float bias = (nt >= 8) ? be1[l*128 + ncl] : 0.0f;
            s_mimj[(mt*16 + quad*4 + 0)*264 + c] = f2bf(acc.x + bias);
            s_mimj[(mt*16 + quad*4 + 1)*264 + c] = f2bf(acc.y + bias);
            s_mimj[(mt*16 + quad*4 + 2)*264 + c] = f2bf(acc.z + bias);
            s_mimj[(mt*16 + quad*4 + 3)*264 + c] = f2bf(acc.w + bias);
        }
        __syncthreads();

        // ---- pair phase: silu1 -> sparse/dense @We2 -> silu2 -> mask -> agg ----
        {
            const unsigned short* we2t = wt + (((size_t)l*6 + 2) << 14);
            const unsigned short* bbase = we2t + lm*128 + quad*8;   // + nt*2048
            bf16x8 b0 = *(const bf16x8*)(bbase      );
            bf16x8 b1 = *(const bf16x8*)(bbase +  32);
            bf16x8 b2 = *(const bf16x8*)(bbase +  64);
            bf16x8 b3 = *(const bf16x8*)(bbase +  96);
            #pragma unroll 1
            for (int ii = 0; ii < 8; ii++) {
                const int i = ii*4 + w;               // wave owns row i fully
                const int cnt = s_cnt[i];             // wave-uniform
                const uint4 miu0 = *(const uint4*)&s_mimj[i*264 +  0 + quad*8];
                const uint4 miu1 = *(const uint4*)&s_mimj[i*264 + 32 + quad*8];
                const uint4 miu2 = *(const uint4*)&s_mimj[i*264 + 64 + quad*8];
                const uint4 miu3 = *(const uint4*)&s_mimj[i*264 + 96 + quad*8];
#define MAKE_AF(J, KB, MIU, AF) { \
    const uint4 mju = *(const uint4*)&s_mimj[(J)*264 + 128 + (KB)*32 + quad*8]; \
    const float4 wa = *(const float4*)&s_wd[(KB)*32 + quad*8]; \
    const float4 wb = *(const float4*)&s_wd[(KB)*32 + quad*8 + 4]; \
    uint4 au; \
    au.x = packbf(silu_f(bflo(MIU.x)+bflo(mju.x)+d2v*wa.x), silu_f(bfhi(MIU.x)+bfhi(mju.x)+d2v*wa.y)); \
    au.y = packbf(silu_f(bflo(MIU.y)+bflo(mju.y)+d2v*wa.z), silu_f(bfhi(MIU.y)+bfhi(mju.y)+d2v*wa.w)); \
    au.z = packbf(silu_f(bflo(MIU.z)+bflo(mju.z)+d2v*wb.x), silu_f(bfhi(MIU.z)+bfhi(mju.z)+d2v*wb.y)); \
    au.w = packbf(silu_f(bflo(MIU.w)+bflo(mju.w)+d2v*wb.z), silu_f(bfhi(MIU.w)+bfhi(mju.w)+d2v*wb.w)); \
    AF = __builtin_bit_cast(bf16x8, au); }
                if (cnt <= 16) {
                    // ---- compacted single-tile path (~99.4% of rows) ----
                    const int j = s_nbr[i][lm];       // gathered neighbor (pad=self)
                    const float d2v = s_d2[i*32 + j];
                    bf16x8 a00, a01, a02, a03;
                    MAKE_AF(j, 0, miu0, a00) MAKE_AF(j, 1, miu1, a01)
                    MAKE_AF(j, 2, miu2, a02) MAKE_AF(j, 3, miu3, a03)
                    const int jb0 = quad*4;
                    const float mk00 = (jb0 + 0 < cnt) ? 1.f : 0.f;
                    const float mk01 = (jb0 + 1 < cnt) ? 1.f : 0.f;
                    const float mk02 = (jb0 + 2 < cnt) ? 1.f : 0.f;
                    const float mk03 = (jb0 + 3 < cnt) ? 1.f : 0.f;
                    #pragma unroll 1
                    for (int nt = 0; nt < 8; nt++) {
                        const unsigned short* np = bbase + (((nt + 1) & 7) * 2048);
                        bf16x8 n0 = *(const bf16x8*)(np      );
                        bf16x8 n1 = *(const bf16x8*)(np +  32);
                        bf16x8 n2 = *(const bf16x8*)(np +  64);
                        bf16x8 n3 = *(const bf16x8*)(np +  96);
                        f32x4 ac0 = {0.f,0.f,0.f,0.f};
                        MFMA16(ac0, a00, b0); MFMA16(ac0, a01, b1);
                        MFMA16(ac0, a02, b2); MFMA16(ac0, a03, b3);
                        const float bv = s_be2[nt*16 + lm];
                        float part = mk00*silu_f(ac0.x + bv) + mk01*silu_f(ac0.y + bv)
                                   + mk02*silu_f(ac0.z + bv) + mk03*silu_f(ac0.w + bv);
                        part += __shfl_xor(part, 16);
                        part += __shfl_xor(part, 32);
                        if (lane < 16) s_A2[i*136 + nt*16 + lane] = f2bf(part);
                        b0 = n0; b1 = n1; b2 = n2; b3 = n3;
                    }
                } else {
                    // ---- dense 2-tile fallback (rare) ----
                    bf16x8 a00, a01, a02, a03;
                    bf16x8 a10, a11, a12, a13;
                    {
                        const int j = lm;
                        const float d2v = s_d2[i*32 + j];
                        MAKE_AF(j, 0, miu0, a00) MAKE_AF(j, 1, miu1, a01)
                        MAKE_AF(j, 2, miu2, a02) MAKE_AF(j, 3, miu3, a03)
                    }
                    {
                        const int j = 16 + lm;
                        const float d2v = s_d2[i*32 + j];
                        MAKE_AF(j, 0, miu0, a10) MAKE_AF(j, 1, miu1, a11)
                        MAKE_AF(j, 2, miu2, a12) MAKE_AF(j, 3, miu3, a13)
                    }
                    const int jb0 = quad*4, jb1 = 16 + quad*4;
                    const float mk00 = (s_d2[i*32 + jb0 + 0] < 1.0f && (jb0+0) != i) ? 1.f : 0.f;
                    const float mk01 = (s_d2[i*32 + jb0 + 1] < 1.0f && (jb0+1) != i) ? 1.f : 0.f;
                    const float mk02 = (s_d2[i*32 + jb0 + 2] < 1.0f && (jb0+2) != i) ? 1.f : 0.f;
                    const float mk03 = (s_d2[i*32 + jb0 + 3] < 1.0f && (jb0+3) != i) ? 1.f : 0.f;
                    const float mk10 = (s_d2[i*32 + jb1 + 0] < 1.0f && (jb1+0) != i) ? 1.f : 0.f;
                    const float mk11 = (s_d2[i*32 + jb1 + 1] < 1.0f && (jb1+1) != i) ? 1.f : 0.f;
                    const float mk12 = (s_d2[i*32 + jb1 + 2] < 1.0f && (jb1+2) != i) ? 1.f : 0.f;
                    const float mk13 = (s_d2[i*32 + jb1 + 3] < 1.0f && (jb1+3) != i) ? 1.f : 0.f;
                    #pragma unroll 1
                    for (int nt = 0; nt < 8; nt++) {
                        const unsigned short* np = bbase + (((nt + 1) & 7) * 2048);
                        bf16x8 n0 = *(const bf16x8*)(np      );
                        bf16x8 n1 = *(const bf16x8*)(np +  32);
                        bf16x8 n2 = *(const bf16x8*)(np +  64);
                        bf16x8 n3 = *(const bf16x8*)(np +  96);
                        f32x4 ac0 = {0.f,0.f,0.f,0.f};
                        f32x4 ac1 = {0.f,0.f,0.f,0.f};
                        MFMA16(ac0, a00, b0); MFMA16(ac0, a01, b1);
                        MFMA16(ac0, a02, b2); MFMA16(ac0, a03, b3);
                        MFMA16(ac1, a10, b0); MFMA16(ac1, a11, b1);
                        MFMA16(ac1, a12, b2); MFMA16(ac1, a13, b3);
                        const float bv = s_be2[nt*16 + lm];
                        float part = mk00*silu_f(ac0.x + bv) + mk01*silu_f(ac0.y + bv)
                                   + mk02*silu_f(ac0.z + bv) + mk03*silu_f(ac0.w + bv)
                                   + mk10*silu_f(ac1.x + bv) + mk11*silu_f(ac1.y + bv)
                                   + mk12*silu_f(ac1.z + bv) + mk13*silu_f(ac1.w + bv);
                        part += __shfl_xor(part, 16);
                        part += __shfl_xor(part, 32);
                        if (lane < 16) s_A2[i*136 + nt*16 + lane] = f2bf(part);
                        b0 = n0; b1 = n1; b2 = n2; b3 = n3;
                    }
                }
#undef MAKE_AF
            }
        }
        __syncthreads();

        // ---- u = silu(hg@Wh1a + agg@Wh1b + bh1) -> s_u (reuses s_mimj, stride 136) ----
        unsigned short* s_u = s_mimj;
        {
            const unsigned short* w1a = wt + (((size_t)l*6 + 3) << 14);
            const unsigned short* w1b = wt + (((size_t)l*6 + 4) << 14);
#define U_GEMM(T2) { \
    const int nt = ng + (T2)*2, ncl = nt*16 + lm; \
    f32x4 acc = {0.f,0.f,0.f,0.f}; \
    _Pragma("unroll") \
    for (int kb = 0; kb < 4; kb++) { \
        bf16x8 a  = *(const bf16x8*)&s_A1[(mt*16+lm)*136 + kb*32 + quad*8]; \
        bf16x8 bb = *(const bf16x8*)&w1a[ncl*128 + kb*32 + quad*8]; \
        MFMA16(acc, a, bb); } \
    _Pragma("unroll") \
    for (int kb = 0; kb < 4; kb++) { \
        bf16x8 a  = *(const bf16x8*)&s_A2[(mt*16+lm)*136 + kb*32 + quad*8]; \
        bf16x8 bb = *(const bf16x8*)&w1b[ncl*128 + kb*32 + quad*8]; \
        MFMA16(acc, a, bb); } \
    const float bh = bh1[l*128 + ncl]; \
    s_u[(mt*16 + quad*4 + 0)*136 + ncl] = f2bf(silu_f(acc.x + bh)); \
    s_u[(mt*16 + quad*4 + 1)*136 + ncl] = f2bf(silu_f(acc.y + bh)); \
    s_u[(mt*16 + quad*4 + 2)*136 + ncl] = f2bf(silu_f(acc.z + bh)); \
    s_u[(mt*16 + quad*4 + 3)*136 + ncl] = f2bf(silu_f(acc.w + bh)); }
            U_GEMM(0) U_GEMM(1) U_GEMM(2) U_GEMM(3)
#undef U_GEMM
        }
        __syncthreads();

        // ---- hg += u@Wh2 + bh2 ----
        {
            const unsigned short* w2 = wt + (((size_t)l*6 + 5) << 14);
#define H_GEMM(T2) { \
    const int nt = ng + (T2)*2, ncl = nt*16 + lm; \
    f32x4 acc = {0.f,0.f,0.f,0.f}; \
    _Pragma("unroll") \
    for (int kb = 0; kb < 4; kb++) { \
        bf16x8 a  = *(const bf16x8*)&s_u[(mt*16+lm)*136 + kb*32 + quad*8]; \
        bf16x8 bb = *(const bf16x8*)&w2[ncl*128 + kb*32 + quad*8]; \
        MFMA16(acc, a, bb); } \
    const float bh = bh2[l*128 + ncl]; \
    s_hg[(mt*16 + quad*4 + 0)*129 + ncl] += acc.x + bh; \
    s_hg[(mt*16 + quad*4 + 1)*129 + ncl] += acc.y + bh; \
    s_hg[(mt*16 + quad*4 + 2)*129 + ncl] += acc.z + bh; \
    s_hg[(mt*16 + quad*4 + 3)*129 + ncl] += acc.w + bh; }
            H_GEMM(0) H_GEMM(1) H_GEMM(2) H_GEMM(3)
#undef H_GEMM
        }
        __syncthreads();
    }

    // ---- output head ----
    {
        int m = tid >> 3, c = (tid & 7) * 16;
        const float* hp = &s_hg[m*129 + c];
        uint4 pa, pb;
        pa.x = packbf(hp[0],  hp[1]);  pa.y = packbf(hp[2],  hp[3]);
        pa.z = packbf(hp[4],  hp[5]);  pa.w = packbf(hp[6],  hp[7]);
        pb.x = packbf(hp[8],  hp[9]);  pb.y = packbf(hp[10], hp[11]);
        pb.z = packbf(hp[12], hp[13]); pb.w = packbf(hp[14], hp[15]);
        *(uint4*)&s_A1[m*136 + c]     = pa;
        *(uint4*)&s_A1[m*136 + c + 8] = pb;
    }
    __syncthreads();
    {   // ho = hg@W_out + b_out -> A2 (bf16)
        const unsigned short* wo = wt + ((size_t)12 << 14);
#define O_GEMM(T2) { \
    const int nt = ng + (T2)*2, ncl = nt*16 + lm; \
    f32x4 acc = {0.f,0.f,0.f,0.f}; \
    _Pragma("unroll") \
    for (int kb = 0; kb < 4; kb++) { \
        bf16x8 a  = *(const bf16x8*)&s_A1[(mt*16+lm)*136 + kb*32 + quad*8]; \
        bf16x8 bb = *(const bf16x8*)&wo[ncl*128 + kb*32 + quad*8]; \
        MFMA16(acc, a, bb); } \
    const float bo = b_out[ncl]; \
    s_A2[(mt*16 + quad*4 + 0)*136 + ncl] = f2bf(acc.x + bo); \
    s_A2[(mt*16 + quad*4 + 1)*136 + ncl] = f2bf(acc.y + bo); \
    s_A2[(mt*16 + quad*4 + 2)*136 + ncl] = f2bf(acc.z + bo); \
    s_A2[(mt*16 + quad*4 + 3)*136 + ncl] = f2bf(acc.w + bo); }
        O_GEMM(0) O_GEMM(1) O_GEMM(2) O_GEMM(3)
#undef O_GEMM
    }
    __syncthreads();
    float* s_g = (float*)s_mimj;                           // reuse (g is 32x129 fp32)
    {   // g = silu(ho@Wn1 + bn1) -> s_g fp32
        const unsigned short* wn1 = wt + ((size_t)13 << 14);
#define G_GEMM(T2) { \
    const int nt = ng + (T2)*2, ncl = nt*16 + lm; \
    f32x4 acc = {0.f,0.f,0.f,0.f}; \
    _Pragma("unroll") \
    for (int kb = 0; kb < 4; kb++) { \
        bf16x8 a  = *(const bf16x8*)&s_A2[(mt*16+lm)*136 + kb*32 + quad*8]; \
        bf16x8 bb = *(const bf16x8*)&wn1[ncl*128 + kb*32 + quad*8]; \
        MFMA16(acc, a, bb); } \
    const float bn = bn1[ncl]; \
    s_g[(mt*16 + quad*4 + 0)*129 + ncl] = silu_f(acc.x + bn); \
    s_g[(mt*16 + quad*4 + 1)*129 + ncl] = silu_f(acc.y + bn); \
    s_g[(mt*16 + quad*4 + 2)*129 + ncl] = silu_f(acc.z + bn); \
    s_g[(mt*16 + quad*4 + 3)*129 + ncl] = silu_f(acc.w + bn); }
        G_GEMM(0) G_GEMM(1) G_GEMM(2) G_GEMM(3)
#undef G_GEMM
    }
    __syncthreads();
    // e = g @ Wn2 + bn2 ; out[b] = sum_m e[m]
    {
        int m = tid >> 3, s = tid & 7;
        float acc = 0.f;
        #pragma unroll
        for (int q = 0; q < 16; q++) {
            int hh = s*16 + q;
            acc += s_g[m*129 + hh] * Wn2[hh];
        }
        s_ep[tid] = acc;
    }
    __syncthreads();
    if (tid < 32) {
        float e = bn2[0];
        #pragma unroll
        for (int s = 0; s < 8; s++) e += s_ep[tid*8 + s];
        #pragma unroll
        for (int off = 16; off >= 1; off >>= 1) e += __shfl_down(e, off, 32);
        if (tid == 0) out[b] = e;
    }
}

extern "C" void kernel_launch(void* const* d_in, const int* in_sizes, int n_in,
                              void* d_out, int out_size, void* d_ws, size_t ws_size,
                              hipStream_t stream) {
    const float* h     = (const float*)d_in[0];
    const float* x     = (const float*)d_in[1];
    const float* W_in  = (const float*)d_in[3];
    const float* b_in  = (const float*)d_in[4];
    const float* We1   = (const float*)d_in[5];
    const float* be1   = (const float*)d_in[6];
    const float* We2   = (const float*)d_in[7];
    const float* be2   = (const float*)d_in[8];
    const float* Wh1   = (const float*)d_in[9];
    const float* bh1   = (const float*)d_in[10];
    const float* Wh2   = (const float*)d_in[11];
    const float* bh2   = (const float*)d_in[12];
    const float* W_out = (const float*)d_in[13];
    const float* b_out = (const float*)d_in[14];
    const float* Wn1   = (const float*)d_in[15];
    const float* bn1   = (const float*)d_in[16];
    const float* Wn2   = (const float*)d_in[17];
    const float* bn2   = (const float*)d_in[18];
    unsigned short* ws = (unsigned short*)d_ws;   // needs 14*16384*2 = 448 KB
    float* outp = (float*)d_out;

    prep_weights<<<14*16, 256, 0, stream>>>(We1, We2, Wh1, Wh2, W_out, Wn1, ws);
    sake_kernel<<<NB, 256, 0, stream>>>(h, x, W_in, b_in, We1, be1, be2, bh1, bh2,
                                        b_out, bn1, Wn2, bn2, ws, outp);
}